// Round 1
// baseline (373.444 us; speedup 1.0000x reference)
//
#include <hip/hip_runtime.h>
#include <hip/hip_bf16.h>

#define T_LEN 2048
#define E_LEN 2048
#define B_SZ  8
#define BM 128
#define BN 128
#define BK 32
#define WREV_LEN 4104   // 2*T + 8, even -> each copy 16B aligned

typedef short short8 __attribute__((ext_vector_type(8)));
typedef float floatx4 __attribute__((ext_vector_type(4)));

// ---------------------------------------------------------------------------
// Prepass 1: xT[b][e][t] = bf16(x[b][t][e])   (tiled transpose via LDS)
// grid: (T/32, E/32, B), block 256
// ---------------------------------------------------------------------------
__global__ __launch_bounds__(256) void transpose_cast(
    const float* __restrict__ x, __hip_bfloat16* __restrict__ xT)
{
    int t0 = blockIdx.x * 32, e0 = blockIdx.y * 32, b = blockIdx.z;
    __shared__ float tile[32][33];
    int tx = threadIdx.x & 31, ty = threadIdx.x >> 5;  // ty in 0..7
    const float* xb = x + (size_t)b * T_LEN * E_LEN;
    #pragma unroll
    for (int r = 0; r < 4; ++r) {
        tile[ty + 8 * r][tx] = xb[(size_t)(t0 + ty + 8 * r) * E_LEN + e0 + tx];
    }
    __syncthreads();
    __hip_bfloat16* xTb = xT + (size_t)b * E_LEN * T_LEN;
    #pragma unroll
    for (int r = 0; r < 4; ++r) {
        xTb[(size_t)(e0 + ty + 8 * r) * T_LEN + t0 + tx] =
            __float2bfloat16(tile[tx][ty + 8 * r]);
    }
}

// ---------------------------------------------------------------------------
// Prepass 2: build 8 shift-staggered bf16 copies of the reversed weight.
//   wrev[j] = (j < T) ? w[T-1-j] : 0        for j in [0, 2T)
//   wrevs[p][q] = wrev[q + p], q in [0, WREV_LEN)
// Then wrev[C..C+7] = 16B-aligned load from copy p=C&7 at element (C-p).
// ---------------------------------------------------------------------------
__global__ __launch_bounds__(256) void build_wrevs(
    const float* __restrict__ w, __hip_bfloat16* __restrict__ wrevs)
{
    int total = 8 * WREV_LEN;
    for (int i = threadIdx.x + blockIdx.x * blockDim.x; i < total;
         i += blockDim.x * gridDim.x) {
        int p = i / WREV_LEN, q = i - p * WREV_LEN;
        int j = q + p;
        float v = (j < T_LEN) ? w[T_LEN - 1 - j] : 0.0f;
        wrevs[i] = __float2bfloat16(v);
    }
}

// ---------------------------------------------------------------------------
// Main GEMM: D[e,s] = sum_t xT[b][e][t] * w[s-t]  (== out[b][s][e])
// A-operand: xT tile [BM=128 e][BK=32 t] staged in LDS (k-contiguous).
// B-operand: fragments loaded straight from wrevs (global, L1-hot).
// Causal skip: only t < s0+BN contributes.
// grid: (E/BM, T/BN, B), block 256 (4 waves, each a 64x64 quadrant, 4x4 MFMA)
// ---------------------------------------------------------------------------
__global__ __launch_bounds__(256) void toeplitz_gemm(
    const __hip_bfloat16* __restrict__ xT,
    const __hip_bfloat16* __restrict__ wrevs,
    const float* __restrict__ bias,
    float* __restrict__ out)
{
    int mb = blockIdx.x, nb = blockIdx.y, b = blockIdx.z;
    int e0 = mb * BM, s0 = nb * BN;
    int tid = threadIdx.x;
    int wave = tid >> 6, lane = tid & 63;
    int wm = (wave & 1) * 64;      // wave's m (e) offset in block tile
    int wn = (wave >> 1) * 64;     // wave's n (s) offset in block tile
    int ln15 = lane & 15, quad = lane >> 4;

    __shared__ __hip_bfloat16 Atile[BM][BK];   // 8 KB

    floatx4 acc[4][4];
    #pragma unroll
    for (int i = 0; i < 4; ++i)
        #pragma unroll
        for (int j = 0; j < 4; ++j)
            acc[i][j] = (floatx4){0.f, 0.f, 0.f, 0.f};

    const int ktiles = (s0 + BN) / BK;   // causal bound (<= T/BK)
    const __hip_bfloat16* xTb = xT + ((size_t)b * E_LEN + e0) * T_LEN;
    const short* wr = reinterpret_cast<const short*>(wrevs);

    for (int kt = 0; kt < ktiles; ++kt) {
        const int t0 = kt * BK;
        __syncthreads();
        // stage A tile: 8KB / 256 threads = 2 x 16B per thread
        #pragma unroll
        for (int i = 0; i < 2; ++i) {
            int c = tid + i * 256;        // 16B-chunk index, tile row = 4 chunks
            int r = c >> 2, p = c & 3;
            const int4* gsrc =
                reinterpret_cast<const int4*>(xTb + (size_t)r * T_LEN + t0) + p;
            reinterpret_cast<int4*>(&Atile[r][0])[p] = *gsrc;
        }
        __syncthreads();

        // B fragments: one 16B aligned global load each (L1-resident weights)
        short8 bfrag[4];
        #pragma unroll
        for (int ni = 0; ni < 4; ++ni) {
            int s = s0 + wn + ni * 16 + ln15;
            int C = (T_LEN - 1) - s + t0 + quad * 8;   // need wrev[C + j]
            int p = C & 7;
            bfrag[ni] = *reinterpret_cast<const short8*>(
                wr + (size_t)p * WREV_LEN + (C - p));
        }
        // A fragments: ds_read_b128 each
        short8 afrag[4];
        #pragma unroll
        for (int mi = 0; mi < 4; ++mi) {
            int r = wm + mi * 16 + ln15;
            afrag[mi] = *reinterpret_cast<const short8*>(&Atile[r][quad * 8]);
        }
        #pragma unroll
        for (int mi = 0; mi < 4; ++mi)
            #pragma unroll
            for (int ni = 0; ni < 4; ++ni)
                acc[mi][ni] = __builtin_amdgcn_mfma_f32_16x16x32_bf16(
                    afrag[mi], bfrag[ni], acc[mi][ni], 0, 0, 0);
    }

    // epilogue: out[b][s][e] = acc + bias[s]
    // C/D layout: col(=s) = lane&15, row(=e) = quad*4 + reg
    #pragma unroll
    for (int ni = 0; ni < 4; ++ni) {
        int s = s0 + wn + ni * 16 + ln15;
        float bv = bias[s];
        #pragma unroll
        for (int mi = 0; mi < 4; ++mi) {
            int e = e0 + wm + mi * 16 + quad * 4;
            float* dst = out + ((size_t)b * T_LEN + s) * E_LEN + e;
            floatx4 v = acc[mi][ni];
            v.x += bv; v.y += bv; v.z += bv; v.w += bv;
            *reinterpret_cast<floatx4*>(dst) = v;
        }
    }
}

// ---------------------------------------------------------------------------
extern "C" void kernel_launch(void* const* d_in, const int* in_sizes, int n_in,
                              void* d_out, int out_size, void* d_ws, size_t ws_size,
                              hipStream_t stream)
{
    const float* x    = (const float*)d_in[0];
    const float* w    = (const float*)d_in[1];
    const float* bias = (const float*)d_in[2];
    float* out = (float*)d_out;

    // workspace layout: [xT bf16: B*E*T] [wrevs bf16: 8*WREV_LEN]
    __hip_bfloat16* xT = (__hip_bfloat16*)d_ws;
    __hip_bfloat16* wrevs =
        (__hip_bfloat16*)((char*)d_ws + (size_t)B_SZ * E_LEN * T_LEN * 2);

    transpose_cast<<<dim3(T_LEN / 32, E_LEN / 32, B_SZ), 256, 0, stream>>>(x, xT);
    build_wrevs<<<dim3(64), 256, 0, stream>>>(w, wrevs);
    toeplitz_gemm<<<dim3(E_LEN / BM, T_LEN / BN, B_SZ), 256, 0, stream>>>(
        xT, wrevs, bias, out);
}

// Round 2
// 340.312 us; speedup vs baseline: 1.0974x; 1.0974x over previous
//
#include <hip/hip_runtime.h>
#include <hip/hip_bf16.h>

#define T_LEN 2048
#define E_LEN 2048
#define B_SZ  8
#define BM 128
#define BN 128
#define BK2 64          // k-tile (two 32-k MFMA sub-steps per barrier pair)
#define WREV_LEN 4104   // 2*T + 8, even -> each shifted copy stays 16B aligned

typedef short short8 __attribute__((ext_vector_type(8)));
typedef float floatx4 __attribute__((ext_vector_type(4)));

typedef const __attribute__((address_space(1))) void* gas_ptr;
typedef __attribute__((address_space(3))) void* lds_ptr;

// ---------------------------------------------------------------------------
// Prepass 1: xT[b][e][t] = bf16(x[b][t][e])
// 64x64 tiles: coalesced float4 loads -> padded fp32 LDS -> conflict-free
// column reads (per instr: lane = e, stride-1) -> packed 16B short8 stores.
// grid: (T/64, E/64, B), block 256
// ---------------------------------------------------------------------------
__global__ __launch_bounds__(256) void transpose_cast(
    const float* __restrict__ x, __hip_bfloat16* __restrict__ xT)
{
    const int t0 = blockIdx.x * 64, e0 = blockIdx.y * 64, b = blockIdx.z;
    __shared__ float tile[64][68];           // +4 pad: column reads spread banks
    const int tid = threadIdx.x;
    const int wave = tid >> 6, lane = tid & 63;

    const float* xb = x + (size_t)b * T_LEN * E_LEN;
    // load: 4 iters, each 16-lane group reads one full 64-float row segment
    #pragma unroll
    for (int i = 0; i < 4; ++i) {
        int row = i * 16 + (tid >> 4);
        int c4  = tid & 15;
        const float4 v = *reinterpret_cast<const float4*>(
            xb + (size_t)(t0 + row) * E_LEN + e0 + c4 * 4);
        *reinterpret_cast<float4*>(&tile[row][c4 * 4]) = v;
    }
    __syncthreads();

    __hip_bfloat16* xTb = xT + (size_t)b * E_LEN * T_LEN;
    // store: per instr all 64 lanes read tile[t][lane] -> stride-1, no conflict
    #pragma unroll
    for (int i = 0; i < 2; ++i) {
        int g = wave + i * 4;                // t-chunk 0..7
        short8 pack;
        #pragma unroll
        for (int j = 0; j < 8; ++j) {
            __hip_bfloat16 h = __float2bfloat16(tile[g * 8 + j][lane]);
            pack[j] = *reinterpret_cast<const short*>(&h);
        }
        *reinterpret_cast<short8*>(
            xTb + (size_t)(e0 + lane) * T_LEN + t0 + g * 8) = pack;
    }
}

// ---------------------------------------------------------------------------
// Prepass 2: 8 shift-staggered bf16 copies of the reversed, zero-padded weight.
//   wrev[j] = (j < T) ? w[T-1-j] : 0 ;  wrevs[p][q] = wrev[q + p]
// => wrev[C..C+7] is one 16B-aligned load from copy p=C&7 at (C-p).
// ---------------------------------------------------------------------------
__global__ __launch_bounds__(256) void build_wrevs(
    const float* __restrict__ w, __hip_bfloat16* __restrict__ wrevs)
{
    int total = 8 * WREV_LEN;
    for (int i = threadIdx.x + blockIdx.x * blockDim.x; i < total;
         i += blockDim.x * gridDim.x) {
        int p = i / WREV_LEN, q = i - p * WREV_LEN;
        int j = q + p;
        float v = (j < T_LEN) ? w[T_LEN - 1 - j] : 0.0f;
        wrevs[i] = __float2bfloat16(v);
    }
}

// ---------------------------------------------------------------------------
// Main GEMM: D[e,s] = sum_t xT[b][e][t] * w[s-t]   (== out[b][s][e])
// A: xT tile [BM=128 e][BK2=64 t] staged with global_load_lds (16B chunks).
// B: fragments read straight from wrevs (L2-hot, no LDS).
// Causal: ktiles = (s0+BN)/64. Heavy-first: nb = 15 - blockIdx.y.
// grid: (16*8, 16)  block 256 (4 waves, 64x64 quadrant each, 4x4 MFMA)
// ---------------------------------------------------------------------------
__global__ __launch_bounds__(256) void toeplitz_gemm(
    const __hip_bfloat16* __restrict__ xT,
    const __hip_bfloat16* __restrict__ wrevs,
    const float* __restrict__ bias,
    float* __restrict__ out)
{
    const int bx = blockIdx.x;
    const int mb = bx & 15, b = bx >> 4;
    const int nb = 15 - (int)blockIdx.y;     // heavy tiles dispatch first
    const int e0 = mb * BM, s0 = nb * BN;
    const int tid = threadIdx.x;
    const int wave = tid >> 6, lane = tid & 63;
    const int wm = (wave & 1) * 64;          // wave m (e) offset
    const int wn = (wave >> 1) * 64;         // wave n (s) offset
    const int ln15 = lane & 15, quad = lane >> 4;

    __shared__ __hip_bfloat16 Atile[BM][BK2];   // 16 KB

    floatx4 acc[4][4];
    #pragma unroll
    for (int i = 0; i < 4; ++i)
        #pragma unroll
        for (int j = 0; j < 4; ++j)
            acc[i][j] = (floatx4){0.f, 0.f, 0.f, 0.f};

    const int ktiles = (s0 + BN) / BK2;      // causal bound
    const __hip_bfloat16* xTb = xT + ((size_t)b * E_LEN + e0) * T_LEN;
    const short* wr = reinterpret_cast<const short*>(wrevs);
    char* AtileB = reinterpret_cast<char*>(&Atile[0][0]);

    for (int kt = 0; kt < ktiles; ++kt) {
        const int t0 = kt * BK2;
        __syncthreads();
        // stage 16 KB: 4 waves x 4 calls x 64 lanes x 16B, LDS dest contiguous
        #pragma unroll
        for (int j = 0; j < 4; ++j) {
            const int c0 = (wave * 4 + j) * 64;    // wave-uniform chunk base
            const int c  = c0 + lane;
            const int r  = c >> 3, p = c & 7;      // row, 16B-col within row
            const __hip_bfloat16* g = xTb + (size_t)r * T_LEN + t0 + p * 8;
            __builtin_amdgcn_global_load_lds(
                (gas_ptr)g, (lds_ptr)(AtileB + (size_t)c0 * 16), 16, 0, 0);
        }
        __syncthreads();

        #pragma unroll
        for (int kk = 0; kk < 2; ++kk) {
            // B fragments: one 16B aligned global load each (L2-resident)
            short8 bfrag[4];
            #pragma unroll
            for (int ni = 0; ni < 4; ++ni) {
                int s = s0 + wn + ni * 16 + ln15;
                int C = (T_LEN - 1) - s + t0 + kk * 32 + quad * 8;
                int p = C & 7;
                bfrag[ni] = *reinterpret_cast<const short8*>(
                    wr + (size_t)p * WREV_LEN + (C - p));
            }
            // A fragments: ds_read_b128
            short8 afrag[4];
            #pragma unroll
            for (int mi = 0; mi < 4; ++mi) {
                int r = wm + mi * 16 + ln15;
                afrag[mi] = *reinterpret_cast<const short8*>(
                    &Atile[r][kk * 32 + quad * 8]);
            }
            #pragma unroll
            for (int mi = 0; mi < 4; ++mi)
                #pragma unroll
                for (int ni = 0; ni < 4; ++ni)
                    acc[mi][ni] = __builtin_amdgcn_mfma_f32_16x16x32_bf16(
                        afrag[mi], bfrag[ni], acc[mi][ni], 0, 0, 0);
        }
    }

    // epilogue: out[b][s][e] = acc + bias[s]
    // C/D layout: col(=s) = lane&15, row(=e) = quad*4 + reg
    #pragma unroll
    for (int ni = 0; ni < 4; ++ni) {
        int s = s0 + wn + ni * 16 + ln15;
        float bv = bias[s];
        #pragma unroll
        for (int mi = 0; mi < 4; ++mi) {
            int e = e0 + wm + mi * 16 + quad * 4;
            float* dst = out + ((size_t)b * T_LEN + s) * E_LEN + e;
            floatx4 v = acc[mi][ni];
            v.x += bv; v.y += bv; v.z += bv; v.w += bv;
            *reinterpret_cast<floatx4*>(dst) = v;
        }
    }
}

// ---------------------------------------------------------------------------
extern "C" void kernel_launch(void* const* d_in, const int* in_sizes, int n_in,
                              void* d_out, int out_size, void* d_ws, size_t ws_size,
                              hipStream_t stream)
{
    const float* x    = (const float*)d_in[0];
    const float* w    = (const float*)d_in[1];
    const float* bias = (const float*)d_in[2];
    float* out = (float*)d_out;

    // workspace: [xT bf16: B*E*T] [wrevs bf16: 8*WREV_LEN]
    __hip_bfloat16* xT = (__hip_bfloat16*)d_ws;
    __hip_bfloat16* wrevs =
        (__hip_bfloat16*)((char*)d_ws + (size_t)B_SZ * E_LEN * T_LEN * 2);

    transpose_cast<<<dim3(T_LEN / 64, E_LEN / 64, B_SZ), 256, 0, stream>>>(x, xT);
    build_wrevs<<<dim3(64), 256, 0, stream>>>(w, wrevs);
    toeplitz_gemm<<<dim3(16 * B_SZ, 16), 256, 0, stream>>>(xT, wrevs, bias, out);
}

// Round 3
// 336.399 us; speedup vs baseline: 1.1101x; 1.0116x over previous
//
#include <hip/hip_runtime.h>
#include <hip/hip_bf16.h>

#define T_LEN 2048
#define E_LEN 2048
#define B_SZ  8
#define BM 128
#define BN 128
#define BK2 64          // k-tile (two 32-k MFMA sub-steps per barrier pair)
#define WREV_LEN 4104   // 2*T + 8, even -> each shifted copy stays 16B aligned

typedef short short8 __attribute__((ext_vector_type(8)));
typedef float floatx4 __attribute__((ext_vector_type(4)));

typedef const __attribute__((address_space(1))) void* gas_ptr;
typedef __attribute__((address_space(3))) void* lds_ptr;

// ---------------------------------------------------------------------------
// Prepass 1: xT[b][e][t] = bf16(x[b][t][e])
// 64t x 64e tiles. LDS holds packed t-pairs: W[e][p] = (x[2p][e], x[2p+1][e])
// as one 4B word (low short = even t). Row stride 33 words -> both LDS phases
// conflict-free. Global: loads float4 (lanes->e, coalesced); stores 4B words
// (lanes->t, 128B contiguous per e-row, full-line coverage).
// grid: (T/64, E/64, B), block 256
// ---------------------------------------------------------------------------
__global__ __launch_bounds__(256) void transpose_cast(
    const float* __restrict__ x, __hip_bfloat16* __restrict__ xT)
{
    const int t0 = blockIdx.x * 64, e0 = blockIdx.y * 64, b = blockIdx.z;
    __shared__ unsigned int W[64][33];       // [e][t-pair], 8448 B
    const int tid = threadIdx.x;
    const int wave = tid >> 6, lane = tid & 63;

    const float* xb = x + (size_t)b * T_LEN * E_LEN;
    const int c = tid & 15;                  // e-quad index (e = 4c..4c+3)
    const int q = tid >> 4;                  // t-pair base (0..15)

    #pragma unroll
    for (int i = 0; i < 2; ++i) {
        const int tp = q + 16 * i;           // t-pair 0..31
        const float4 a4 = *reinterpret_cast<const float4*>(
            xb + (size_t)(t0 + 2 * tp) * E_LEN + e0 + 4 * c);
        const float4 b4 = *reinterpret_cast<const float4*>(
            xb + (size_t)(t0 + 2 * tp + 1) * E_LEN + e0 + 4 * c);
        const float av[4] = {a4.x, a4.y, a4.z, a4.w};
        const float bv[4] = {b4.x, b4.y, b4.z, b4.w};
        #pragma unroll
        for (int j = 0; j < 4; ++j) {
            __hip_bfloat16 ha = __float2bfloat16(av[j]);
            __hip_bfloat16 hb = __float2bfloat16(bv[j]);
            unsigned int w =
                (unsigned int)*reinterpret_cast<unsigned short*>(&ha) |
                ((unsigned int)*reinterpret_cast<unsigned short*>(&hb) << 16);
            W[4 * c + j][tp] = w;
        }
    }
    __syncthreads();

    __hip_bfloat16* xTb = xT + (size_t)b * E_LEN * T_LEN;
    const int p = lane & 31;                 // t-pair covered by this lane
    const int er = lane >> 5;                // e-row within instr (0/1)
    #pragma unroll
    for (int i = 0; i < 8; ++i) {
        const int e = wave * 2 + i * 8 + er; // 0..63
        unsigned int w = W[e][p];
        reinterpret_cast<unsigned int*>(
            xTb + (size_t)(e0 + e) * T_LEN + t0)[p] = w;
    }
}

// ---------------------------------------------------------------------------
// Prepass 2: 8 shift-staggered bf16 copies of the reversed, zero-padded weight.
//   wrev[j] = (j < T) ? w[T-1-j] : 0 ;  wrevs[p][q] = wrev[q + p]
// => wrev[C..C+7] is one 16B-aligned load from copy p=C&7 at (C-p).
// ---------------------------------------------------------------------------
__global__ __launch_bounds__(256) void build_wrevs(
    const float* __restrict__ w, __hip_bfloat16* __restrict__ wrevs)
{
    int total = 8 * WREV_LEN;
    for (int i = threadIdx.x + blockIdx.x * blockDim.x; i < total;
         i += blockDim.x * gridDim.x) {
        int p = i / WREV_LEN, q = i - p * WREV_LEN;
        int j = q + p;
        float v = (j < T_LEN) ? w[T_LEN - 1 - j] : 0.0f;
        wrevs[i] = __float2bfloat16(v);
    }
}

// ---------------------------------------------------------------------------
// Main GEMM: D[e,s] = sum_t xT[b][e][t] * w[s-t]   (== out[b][s][e])
// A: xT tile [BM=128 e][BK2=64 t] staged with global_load_lds (16B chunks).
// B: fragments read straight from wrevs (L2-hot, no LDS).
// Causal: ktiles = (s0+BN)/64. Heavy-first: nb = 15 - blockIdx.y.
// grid: (16*8, 16)  block 256 (4 waves, 64x64 quadrant each, 4x4 MFMA)
// ---------------------------------------------------------------------------
__global__ __launch_bounds__(256) void toeplitz_gemm(
    const __hip_bfloat16* __restrict__ xT,
    const __hip_bfloat16* __restrict__ wrevs,
    const float* __restrict__ bias,
    float* __restrict__ out)
{
    const int bx = blockIdx.x;
    const int mb = bx & 15, b = bx >> 4;
    const int nb = 15 - (int)blockIdx.y;     // heavy tiles dispatch first
    const int e0 = mb * BM, s0 = nb * BN;
    const int tid = threadIdx.x;
    const int wave = tid >> 6, lane = tid & 63;
    const int wm = (wave & 1) * 64;          // wave m (e) offset
    const int wn = (wave >> 1) * 64;         // wave n (s) offset
    const int ln15 = lane & 15, quad = lane >> 4;

    __shared__ __hip_bfloat16 Atile[BM][BK2];   // 16 KB

    floatx4 acc[4][4];
    #pragma unroll
    for (int i = 0; i < 4; ++i)
        #pragma unroll
        for (int j = 0; j < 4; ++j)
            acc[i][j] = (floatx4){0.f, 0.f, 0.f, 0.f};

    const int ktiles = (s0 + BN) / BK2;      // causal bound
    const __hip_bfloat16* xTb = xT + ((size_t)b * E_LEN + e0) * T_LEN;
    const short* wr = reinterpret_cast<const short*>(wrevs);
    char* AtileB = reinterpret_cast<char*>(&Atile[0][0]);

    for (int kt = 0; kt < ktiles; ++kt) {
        const int t0 = kt * BK2;
        __syncthreads();
        // stage 16 KB: 4 waves x 4 calls x 64 lanes x 16B, LDS dest contiguous
        #pragma unroll
        for (int j = 0; j < 4; ++j) {
            const int c0 = (wave * 4 + j) * 64;    // wave-uniform chunk base
            const int c  = c0 + lane;
            const int r  = c >> 3, p = c & 7;      // row, 16B-col within row
            const __hip_bfloat16* g = xTb + (size_t)r * T_LEN + t0 + p * 8;
            __builtin_amdgcn_global_load_lds(
                (gas_ptr)g, (lds_ptr)(AtileB + (size_t)c0 * 16), 16, 0, 0);
        }
        __syncthreads();

        #pragma unroll
        for (int kk = 0; kk < 2; ++kk) {
            // B fragments: one 16B aligned global load each (L2-resident)
            short8 bfrag[4];
            #pragma unroll
            for (int ni = 0; ni < 4; ++ni) {
                int s = s0 + wn + ni * 16 + ln15;
                int C = (T_LEN - 1) - s + t0 + kk * 32 + quad * 8;
                int p = C & 7;
                bfrag[ni] = *reinterpret_cast<const short8*>(
                    wr + (size_t)p * WREV_LEN + (C - p));
            }
            // A fragments: ds_read_b128
            short8 afrag[4];
            #pragma unroll
            for (int mi = 0; mi < 4; ++mi) {
                int r = wm + mi * 16 + ln15;
                afrag[mi] = *reinterpret_cast<const short8*>(
                    &Atile[r][kk * 32 + quad * 8]);
            }
            #pragma unroll
            for (int mi = 0; mi < 4; ++mi)
                #pragma unroll
                for (int ni = 0; ni < 4; ++ni)
                    acc[mi][ni] = __builtin_amdgcn_mfma_f32_16x16x32_bf16(
                        afrag[mi], bfrag[ni], acc[mi][ni], 0, 0, 0);
        }
    }

    // epilogue: out[b][s][e] = acc + bias[s]
    // C/D layout: col(=s) = lane&15, row(=e) = quad*4 + reg
    #pragma unroll
    for (int ni = 0; ni < 4; ++ni) {
        int s = s0 + wn + ni * 16 + ln15;
        float bv = bias[s];
        #pragma unroll
        for (int mi = 0; mi < 4; ++mi) {
            int e = e0 + wm + mi * 16 + quad * 4;
            float* dst = out + ((size_t)b * T_LEN + s) * E_LEN + e;
            floatx4 v = acc[mi][ni];
            v.x += bv; v.y += bv; v.z += bv; v.w += bv;
            *reinterpret_cast<floatx4*>(dst) = v;
        }
    }
}

// ---------------------------------------------------------------------------
extern "C" void kernel_launch(void* const* d_in, const int* in_sizes, int n_in,
                              void* d_out, int out_size, void* d_ws, size_t ws_size,
                              hipStream_t stream)
{
    const float* x    = (const float*)d_in[0];
    const float* w    = (const float*)d_in[1];
    const float* bias = (const float*)d_in[2];
    float* out = (float*)d_out;

    // workspace: [xT bf16: B*E*T] [wrevs bf16: 8*WREV_LEN]
    __hip_bfloat16* xT = (__hip_bfloat16*)d_ws;
    __hip_bfloat16* wrevs =
        (__hip_bfloat16*)((char*)d_ws + (size_t)B_SZ * E_LEN * T_LEN * 2);

    transpose_cast<<<dim3(T_LEN / 64, E_LEN / 64, B_SZ), 256, 0, stream>>>(x, xT);
    build_wrevs<<<dim3(64), 256, 0, stream>>>(w, wrevs);
    toeplitz_gemm<<<dim3(16 * B_SZ, 16), 256, 0, stream>>>(xT, wrevs, bias, out);
}